// Round 1
// baseline (1067.422 us; speedup 1.0000x reference)
//
#include <hip/hip_runtime.h>

#define HID 128
#define NNODES 50000
#define NEDGES 800000
#define NGRAPHS 64
#define NLAYERS 2
#define BN_EPS 1e-5f

// ---------------------------------------------------------------------------
// x[n,c] = node_emb[x_idx[n], c]
__global__ __launch_bounds__(128) void embed_kernel(
    const int* __restrict__ x_idx, const float* __restrict__ node_emb,
    float* __restrict__ x) {
  int n = blockIdx.x;
  int c = threadIdx.x;
  x[n * HID + c] = node_emb[x_idx[n] * HID + c];
}

// ---------------------------------------------------------------------------
// aggr[dst] += relu(x[src] + edge_emb[attr]) for every edge.
// blockDim = (128, 2); each block handles EPB edges.
#define EPB 16
__global__ __launch_bounds__(256) void edge_kernel(
    const int* __restrict__ eidx, const int* __restrict__ eattr,
    const float* __restrict__ x, const float* __restrict__ edge_emb,
    float* __restrict__ aggr) {
  int c = threadIdx.x;
  int e0 = blockIdx.x * EPB;
  for (int e = e0 + (int)threadIdx.y; e < e0 + EPB; e += 2) {
    int s = eidx[e];
    int d = eidx[NEDGES + e];
    int a = eattr[e];
    float v = x[s * HID + c] + edge_emb[a * HID + c];
    v = fmaxf(v, 0.0f);
    unsafeAtomicAdd(&aggr[d * HID + c], v);
  }
}

// ---------------------------------------------------------------------------
// h0 = x + aggr; h1 = relu(h0@W1+b1); h2 = relu(h1@W2+b2)
// writes h2 back into aggr; accumulates per-channel sum/sumsq into stats.
// blockDim = 128 (thread = out channel), NB nodes register-blocked.
#define NB 8
__global__ __launch_bounds__(128) void mlp_kernel(
    const float* __restrict__ x, float* __restrict__ aggr,
    const float* __restrict__ W1, const float* __restrict__ b1,
    const float* __restrict__ W2, const float* __restrict__ b2,
    float* __restrict__ stats) {
  __shared__ float hA[NB * HID];
  __shared__ float hB[NB * HID];
  int c = threadIdx.x;
  float lsum = 0.0f, lsq = 0.0f;
  const int ngroups = (NNODES + NB - 1) / NB;  // 6250 exact
  float bias1 = b1[c];
  float bias2 = b2[c];
  for (int g = blockIdx.x; g < ngroups; g += gridDim.x) {
    int base = g * NB;
    #pragma unroll
    for (int n = 0; n < NB; n++) {
      int node = base + n;
      float v = 0.0f;
      if (node < NNODES) v = x[node * HID + c] + aggr[node * HID + c];
      hA[n * HID + c] = v;
    }
    __syncthreads();

    float acc[NB];
    #pragma unroll
    for (int n = 0; n < NB; n++) acc[n] = bias1;
    for (int k = 0; k < HID; k++) {
      float w = W1[k * HID + c];
      #pragma unroll
      for (int n = 0; n < NB; n++) acc[n] = fmaf(hA[n * HID + k], w, acc[n]);
    }
    #pragma unroll
    for (int n = 0; n < NB; n++) hB[n * HID + c] = fmaxf(acc[n], 0.0f);
    __syncthreads();

    #pragma unroll
    for (int n = 0; n < NB; n++) acc[n] = bias2;
    for (int k = 0; k < HID; k++) {
      float w = W2[k * HID + c];
      #pragma unroll
      for (int n = 0; n < NB; n++) acc[n] = fmaf(hB[n * HID + k], w, acc[n]);
    }
    #pragma unroll
    for (int n = 0; n < NB; n++) {
      int node = base + n;
      if (node < NNODES) {
        float h2 = fmaxf(acc[n], 0.0f);
        aggr[node * HID + c] = h2;
        lsum += h2;
        lsq += h2 * h2;
      }
    }
    __syncthreads();
  }
  unsafeAtomicAdd(&stats[c], lsum);
  unsafeAtomicAdd(&stats[HID + c], lsq);
}

// ---------------------------------------------------------------------------
// x[n,c] = g[c]*(h[n,c]-mu[c])*rsqrt(var[c]+eps) + beta[c]
__global__ __launch_bounds__(128) void bn_kernel(
    const float* __restrict__ h, float* __restrict__ x,
    const float* __restrict__ stats, const float* __restrict__ gam,
    const float* __restrict__ bet) {
  int c = threadIdx.x;
  float mu = stats[c] * (1.0f / NNODES);
  float var = stats[HID + c] * (1.0f / NNODES) - mu * mu;
  float scl = gam[c] * rsqrtf(var + BN_EPS);
  float sh = bet[c] - mu * scl;
  for (int n = blockIdx.x; n < NNODES; n += gridDim.x)
    x[n * HID + c] = fmaf(h[n * HID + c], scl, sh);
}

// ---------------------------------------------------------------------------
// pooled[batch[n]] += x[n]  (batch is sorted -> run-length accumulate)
#define PNB 200
__global__ __launch_bounds__(128) void pool_kernel(
    const float* __restrict__ x, const int* __restrict__ batch,
    float* __restrict__ out) {
  int c = threadIdx.x;
  int n0 = blockIdx.x * PNB;
  int n1 = min(n0 + PNB, NNODES);
  if (n0 >= NNODES) return;
  int cur = batch[n0];
  float acc = 0.0f;
  for (int n = n0; n < n1; n++) {
    int g = batch[n];
    if (g != cur) {
      unsafeAtomicAdd(&out[cur * HID + c], acc);
      acc = 0.0f;
      cur = g;
    }
    acc += x[n * HID + c];
  }
  unsafeAtomicAdd(&out[cur * HID + c], acc);
}

// ---------------------------------------------------------------------------
extern "C" void kernel_launch(void* const* d_in, const int* in_sizes, int n_in,
                              void* d_out, int out_size, void* d_ws, size_t ws_size,
                              hipStream_t stream) {
  const int* x_idx = (const int*)d_in[0];
  const int* eidx = (const int*)d_in[1];   // [2, E] row-major: src then dst
  const int* eattr = (const int*)d_in[2];
  const int* batch = (const int*)d_in[3];
  const float* node_emb = (const float*)d_in[4];
  const float* edge_emb = (const float*)d_in[5];
  const float* W1 = (const float*)d_in[6];
  const float* b1 = (const float*)d_in[7];
  const float* W2 = (const float*)d_in[8];
  const float* b2 = (const float*)d_in[9];
  const float* bn_g = (const float*)d_in[10];
  const float* bn_b = (const float*)d_in[11];
  float* out = (float*)d_out;

  float* x = (float*)d_ws;                       // [NNODES, HID]
  float* aggr = x + (size_t)NNODES * HID;        // [NNODES, HID] (also holds h2)
  float* stats = aggr + (size_t)NNODES * HID;    // [2, HID]

  hipMemsetAsync(d_out, 0, (size_t)NGRAPHS * HID * sizeof(float), stream);

  embed_kernel<<<NNODES, 128, 0, stream>>>(x_idx, node_emb, x);

  for (int l = 0; l < NLAYERS; l++) {
    hipMemsetAsync(aggr, 0, (size_t)NNODES * HID * sizeof(float), stream);
    hipMemsetAsync(stats, 0, 2 * HID * sizeof(float), stream);
    edge_kernel<<<NEDGES / EPB, dim3(128, 2), 0, stream>>>(eidx, eattr, x,
                                                           edge_emb, aggr);
    mlp_kernel<<<2048, 128, 0, stream>>>(x, aggr, W1 + (size_t)l * HID * HID,
                                         b1 + l * HID,
                                         W2 + (size_t)l * HID * HID,
                                         b2 + l * HID, stats);
    bn_kernel<<<2048, 128, 0, stream>>>(aggr, x, stats, bn_g + l * HID,
                                        bn_b + l * HID);
  }

  pool_kernel<<<(NNODES + PNB - 1) / PNB, 128, 0, stream>>>(x, batch, out);
}

// Round 2
// 689.379 us; speedup vs baseline: 1.5484x; 1.5484x over previous
//
#include <hip/hip_runtime.h>

#define HID 128
#define NNODES 50000
#define NEDGES 800000
#define NGRAPHS 64
#define NLAYERS 2
#define BN_EPS 1e-5f

// ---------------------------------------------------------------------------
// x[n,c] = node_emb[x_idx[n], c]
__global__ __launch_bounds__(128) void embed_kernel(
    const int* __restrict__ x_idx, const float* __restrict__ node_emb,
    float* __restrict__ x) {
  int n = blockIdx.x;
  int c = threadIdx.x;
  x[n * HID + c] = node_emb[x_idx[n] * HID + c];
}

// ===========================================================================
// CSR build: histogram -> scan -> scatter. Rebuilt every call (same result).
// ===========================================================================
__global__ __launch_bounds__(256) void deg_kernel(
    const int* __restrict__ eidx, int* __restrict__ deg) {
  int e = blockIdx.x * 256 + threadIdx.x;
  if (e < NEDGES) atomicAdd(&deg[eidx[NEDGES + e]], 1);
}

#define SCAN_CHUNK 196  // 256*196 = 50176 >= 50000
// one block, 256 threads: per-chunk sums + exclusive scan of chunk sums
__global__ __launch_bounds__(256) void scan1_kernel(
    const int* __restrict__ deg, int* __restrict__ chunk_base) {
  __shared__ int s[256];
  int t = threadIdx.x;
  int sum = 0;
  for (int i = 0; i < SCAN_CHUNK; i++) {
    int idx = t * SCAN_CHUNK + i;
    if (idx < NNODES) sum += deg[idx];
  }
  s[t] = sum;
  __syncthreads();
  // Hillis-Steele inclusive scan
  for (int off = 1; off < 256; off <<= 1) {
    int v = (t >= off) ? s[t - off] : 0;
    __syncthreads();
    s[t] += v;
    __syncthreads();
  }
  chunk_base[t] = s[t] - sum;  // exclusive
}

// 256 blocks: scan within chunk, write offsets + cursor
__global__ __launch_bounds__(256) void scan2_kernel(
    const int* __restrict__ deg, const int* __restrict__ chunk_base,
    int* __restrict__ offs, int* __restrict__ cursor) {
  __shared__ int s[256];
  int b = blockIdx.x;
  int t = threadIdx.x;
  int idx = b * SCAN_CHUNK + t;
  int val = (t < SCAN_CHUNK && idx < NNODES) ? deg[idx] : 0;
  s[t] = val;
  __syncthreads();
  for (int off = 1; off < 256; off <<= 1) {
    int v = (t >= off) ? s[t - off] : 0;
    __syncthreads();
    s[t] += v;
    __syncthreads();
  }
  if (t < SCAN_CHUNK && idx < NNODES) {
    int excl = chunk_base[b] + s[t] - val;
    offs[idx] = excl;
    cursor[idx] = excl;
  }
  if (b == 0 && t == 0) offs[NNODES] = NEDGES;
}

// eout[pos] = src | (attr<<16)   (src < 65536, attr < 4)
__global__ __launch_bounds__(256) void scatter_kernel(
    const int* __restrict__ eidx, const int* __restrict__ eattr,
    int* __restrict__ cursor, int* __restrict__ eout) {
  int e = blockIdx.x * 256 + threadIdx.x;
  if (e >= NEDGES) return;
  int d = eidx[NEDGES + e];
  int pos = atomicAdd(&cursor[d], 1);
  eout[pos] = eidx[e] | (eattr[e] << 16);
}

// ===========================================================================
// Fused: h0[n] = x[n] + sum_in relu(x[src]+edge_emb[attr]);
//        h2 = relu(relu(h0@W1+b1)@W2+b2); stats += (sum, sumsq)
// ===========================================================================
#define NB 8
#define GRID_MLP 2048
__global__ __launch_bounds__(128) void gine_mlp_kernel(
    const float* __restrict__ x, const int* __restrict__ offs,
    const int* __restrict__ eout, const float* __restrict__ edge_emb,
    const float* __restrict__ W1, const float* __restrict__ b1,
    const float* __restrict__ W2, const float* __restrict__ b2,
    float* __restrict__ h2, float* __restrict__ stats) {
  __shared__ float hA[NB * HID];
  __shared__ float hB[NB * HID];
  int c = threadIdx.x;
  float lsum = 0.0f, lsq = 0.0f;
  const int ngroups = (NNODES + NB - 1) / NB;  // 6250
  float bias1 = b1[c];
  float bias2 = b2[c];
  float ee0 = edge_emb[0 * HID + c];
  float ee1 = edge_emb[1 * HID + c];
  float ee2 = edge_emb[2 * HID + c];
  float ee3 = edge_emb[3 * HID + c];
  for (int g = blockIdx.x; g < ngroups; g += gridDim.x) {
    int base = g * NB;
    #pragma unroll
    for (int n = 0; n < NB; n++) {
      int node = base + n;
      float v = 0.0f;
      if (node < NNODES) {
        v = x[node * HID + c];
        int e0 = offs[node], e1 = offs[node + 1];
        int e = e0;
        for (; e + 1 < e1; e += 2) {  // unroll x2 to overlap gather latency
          int p0 = eout[e], p1 = eout[e + 1];
          int s0 = p0 & 0xFFFF, a0 = p0 >> 16;
          int s1 = p1 & 0xFFFF, a1 = p1 >> 16;
          float x0 = x[s0 * HID + c];
          float x1 = x[s1 * HID + c];
          float eA = (a0 == 0) ? ee0 : (a0 == 1) ? ee1 : (a0 == 2) ? ee2 : ee3;
          float eB = (a1 == 0) ? ee0 : (a1 == 1) ? ee1 : (a1 == 2) ? ee2 : ee3;
          v += fmaxf(x0 + eA, 0.0f) + fmaxf(x1 + eB, 0.0f);
        }
        if (e < e1) {
          int p0 = eout[e];
          int s0 = p0 & 0xFFFF, a0 = p0 >> 16;
          float eA = (a0 == 0) ? ee0 : (a0 == 1) ? ee1 : (a0 == 2) ? ee2 : ee3;
          v += fmaxf(x[s0 * HID + c] + eA, 0.0f);
        }
      }
      hA[n * HID + c] = v;
    }
    __syncthreads();

    float acc[NB];
    #pragma unroll
    for (int n = 0; n < NB; n++) acc[n] = bias1;
    for (int k = 0; k < HID; k++) {
      float w = W1[k * HID + c];
      #pragma unroll
      for (int n = 0; n < NB; n++) acc[n] = fmaf(hA[n * HID + k], w, acc[n]);
    }
    #pragma unroll
    for (int n = 0; n < NB; n++) hB[n * HID + c] = fmaxf(acc[n], 0.0f);
    __syncthreads();

    #pragma unroll
    for (int n = 0; n < NB; n++) acc[n] = bias2;
    for (int k = 0; k < HID; k++) {
      float w = W2[k * HID + c];
      #pragma unroll
      for (int n = 0; n < NB; n++) acc[n] = fmaf(hB[n * HID + k], w, acc[n]);
    }
    #pragma unroll
    for (int n = 0; n < NB; n++) {
      int node = base + n;
      if (node < NNODES) {
        float v = fmaxf(acc[n], 0.0f);
        h2[node * HID + c] = v;
        lsum += v;
        lsq += v * v;
      }
    }
    __syncthreads();
  }
  unsafeAtomicAdd(&stats[c], lsum);
  unsafeAtomicAdd(&stats[HID + c], lsq);
}

// ---------------------------------------------------------------------------
// Fallback path (atomic scatter) kernels — used only if ws_size is too small.
#define EPB 16
__global__ __launch_bounds__(256) void edge_kernel(
    const int* __restrict__ eidx, const int* __restrict__ eattr,
    const float* __restrict__ x, const float* __restrict__ edge_emb,
    float* __restrict__ aggr) {
  int c = threadIdx.x;
  int e0 = blockIdx.x * EPB;
  for (int e = e0 + (int)threadIdx.y; e < e0 + EPB; e += 2) {
    int s = eidx[e];
    int d = eidx[NEDGES + e];
    int a = eattr[e];
    float v = fmaxf(x[s * HID + c] + edge_emb[a * HID + c], 0.0f);
    unsafeAtomicAdd(&aggr[d * HID + c], v);
  }
}

__global__ __launch_bounds__(128) void mlp_kernel(
    const float* __restrict__ x, float* __restrict__ aggr,
    const float* __restrict__ W1, const float* __restrict__ b1,
    const float* __restrict__ W2, const float* __restrict__ b2,
    float* __restrict__ stats) {
  __shared__ float hA[NB * HID];
  __shared__ float hB[NB * HID];
  int c = threadIdx.x;
  float lsum = 0.0f, lsq = 0.0f;
  const int ngroups = (NNODES + NB - 1) / NB;
  float bias1 = b1[c];
  float bias2 = b2[c];
  for (int g = blockIdx.x; g < ngroups; g += gridDim.x) {
    int base = g * NB;
    #pragma unroll
    for (int n = 0; n < NB; n++) {
      int node = base + n;
      float v = 0.0f;
      if (node < NNODES) v = x[node * HID + c] + aggr[node * HID + c];
      hA[n * HID + c] = v;
    }
    __syncthreads();
    float acc[NB];
    #pragma unroll
    for (int n = 0; n < NB; n++) acc[n] = bias1;
    for (int k = 0; k < HID; k++) {
      float w = W1[k * HID + c];
      #pragma unroll
      for (int n = 0; n < NB; n++) acc[n] = fmaf(hA[n * HID + k], w, acc[n]);
    }
    #pragma unroll
    for (int n = 0; n < NB; n++) hB[n * HID + c] = fmaxf(acc[n], 0.0f);
    __syncthreads();
    #pragma unroll
    for (int n = 0; n < NB; n++) acc[n] = bias2;
    for (int k = 0; k < HID; k++) {
      float w = W2[k * HID + c];
      #pragma unroll
      for (int n = 0; n < NB; n++) acc[n] = fmaf(hB[n * HID + k], w, acc[n]);
    }
    #pragma unroll
    for (int n = 0; n < NB; n++) {
      int node = base + n;
      if (node < NNODES) {
        float v = fmaxf(acc[n], 0.0f);
        aggr[node * HID + c] = v;
        lsum += v;
        lsq += v * v;
      }
    }
    __syncthreads();
  }
  unsafeAtomicAdd(&stats[c], lsum);
  unsafeAtomicAdd(&stats[HID + c], lsq);
}

// ---------------------------------------------------------------------------
__global__ __launch_bounds__(128) void bn_kernel(
    const float* __restrict__ h, float* __restrict__ x,
    const float* __restrict__ stats, const float* __restrict__ gam,
    const float* __restrict__ bet) {
  int c = threadIdx.x;
  float mu = stats[c] * (1.0f / NNODES);
  float var = stats[HID + c] * (1.0f / NNODES) - mu * mu;
  float scl = gam[c] * rsqrtf(var + BN_EPS);
  float sh = bet[c] - mu * scl;
  for (int n = blockIdx.x; n < NNODES; n += gridDim.x)
    x[n * HID + c] = fmaf(h[n * HID + c], scl, sh);
}

// ---------------------------------------------------------------------------
#define PNB 200
__global__ __launch_bounds__(128) void pool_kernel(
    const float* __restrict__ x, const int* __restrict__ batch,
    float* __restrict__ out) {
  int c = threadIdx.x;
  int n0 = blockIdx.x * PNB;
  int n1 = min(n0 + PNB, NNODES);
  if (n0 >= NNODES) return;
  int cur = batch[n0];
  float acc = 0.0f;
  for (int n = n0; n < n1; n++) {
    int g = batch[n];
    if (g != cur) {
      unsafeAtomicAdd(&out[cur * HID + c], acc);
      acc = 0.0f;
      cur = g;
    }
    acc += x[n * HID + c];
  }
  unsafeAtomicAdd(&out[cur * HID + c], acc);
}

// ---------------------------------------------------------------------------
extern "C" void kernel_launch(void* const* d_in, const int* in_sizes, int n_in,
                              void* d_out, int out_size, void* d_ws, size_t ws_size,
                              hipStream_t stream) {
  const int* x_idx = (const int*)d_in[0];
  const int* eidx = (const int*)d_in[1];   // [2, E]: src row then dst row
  const int* eattr = (const int*)d_in[2];
  const int* batch = (const int*)d_in[3];
  const float* node_emb = (const float*)d_in[4];
  const float* edge_emb = (const float*)d_in[5];
  const float* W1 = (const float*)d_in[6];
  const float* b1 = (const float*)d_in[7];
  const float* W2 = (const float*)d_in[8];
  const float* b2 = (const float*)d_in[9];
  const float* bn_g = (const float*)d_in[10];
  const float* bn_b = (const float*)d_in[11];
  float* out = (float*)d_out;

  const size_t nfeat = (size_t)NNODES * HID;
  float* x = (float*)d_ws;        // [N, H]
  float* h2 = x + nfeat;          // [N, H]
  float* stats = h2 + nfeat;      // [2, H]
  int* offs = (int*)(stats + 2 * HID);   // [N+1]
  int* cursor = offs + (NNODES + 1);     // [N]
  int* deg = cursor + NNODES;            // [N]
  int* chunk_base = deg + NNODES;        // [256]
  int* eout = chunk_base + 256;          // [E]
  size_t needed = (size_t)((char*)(eout + NEDGES) - (char*)d_ws);

  hipMemsetAsync(d_out, 0, (size_t)NGRAPHS * HID * sizeof(float), stream);
  embed_kernel<<<NNODES, 128, 0, stream>>>(x_idx, node_emb, x);

  if (ws_size >= needed) {
    // CSR build (once; shared by both layers)
    hipMemsetAsync(deg, 0, NNODES * sizeof(int), stream);
    deg_kernel<<<(NEDGES + 255) / 256, 256, 0, stream>>>(eidx, deg);
    scan1_kernel<<<1, 256, 0, stream>>>(deg, chunk_base);
    scan2_kernel<<<256, 256, 0, stream>>>(deg, chunk_base, offs, cursor);
    scatter_kernel<<<(NEDGES + 255) / 256, 256, 0, stream>>>(eidx, eattr,
                                                             cursor, eout);
    for (int l = 0; l < NLAYERS; l++) {
      hipMemsetAsync(stats, 0, 2 * HID * sizeof(float), stream);
      gine_mlp_kernel<<<GRID_MLP, 128, 0, stream>>>(
          x, offs, eout, edge_emb, W1 + (size_t)l * HID * HID, b1 + l * HID,
          W2 + (size_t)l * HID * HID, b2 + l * HID, h2, stats);
      bn_kernel<<<2048, 128, 0, stream>>>(h2, x, stats, bn_g + l * HID,
                                          bn_b + l * HID);
    }
  } else {
    // fallback: atomic-scatter path (round-1 structure), h2 buffer = aggr
    for (int l = 0; l < NLAYERS; l++) {
      hipMemsetAsync(h2, 0, nfeat * sizeof(float), stream);
      hipMemsetAsync(stats, 0, 2 * HID * sizeof(float), stream);
      edge_kernel<<<NEDGES / EPB, dim3(128, 2), 0, stream>>>(eidx, eattr, x,
                                                             edge_emb, h2);
      mlp_kernel<<<GRID_MLP, 128, 0, stream>>>(
          x, h2, W1 + (size_t)l * HID * HID, b1 + l * HID,
          W2 + (size_t)l * HID * HID, b2 + l * HID, stats);
      bn_kernel<<<2048, 128, 0, stream>>>(h2, x, stats, bn_g + l * HID,
                                          bn_b + l * HID);
    }
  }

  pool_kernel<<<(NNODES + PNB - 1) / PNB, 128, 0, stream>>>(x, batch, out);
}